// Round 4
// baseline (5007.882 us; speedup 1.0000x reference)
//
#include <hip/hip_runtime.h>
#include <hip/hip_bf16.h>

#define Hd 512
#define Bd 512
#define Vd 128
#define Sd 256

typedef _Float16 half8 __attribute__((ext_vector_type(8)));
typedef float float4v __attribute__((ext_vector_type(4)));

__device__ __forceinline__ float sigf(float v) { return 1.0f / (1.0f + __expf(-v)); }
__device__ __forceinline__ float tanhfast(float v) { return 1.0f - 2.0f / (__expf(2.0f * v) + 1.0f); }

// ---------------- prep kernels (layouts identical to R3) ----------------
// wxt[dir][v][n] = Wx[g][k][v] + bx[g*H+k] + bh[g*H+k], n = (k<<2)|g. fp32.
__global__ __launch_bounds__(256) void prep_wxt(
    const float* __restrict__ WxF, const float* __restrict__ bxF, const float* __restrict__ bhF,
    const float* __restrict__ WxB, const float* __restrict__ bxB, const float* __restrict__ bhB,
    float* __restrict__ wxt) {
  int e = blockIdx.x * 256 + threadIdx.x;
  int n = e & 2047;
  int v = (e >> 11) & 127;
  int dir = e >> 18;
  int k = n >> 2, g = n & 3;
  const float* Wx = dir ? WxB : WxF;
  const float* bx = dir ? bxB : bxF;
  const float* bh = dir ? bhB : bhF;
  int gk = g * Hd + k;
  wxt[e] = Wx[gk * Vd + v] + bx[gk] + bh[gk];
}

// whr[dir][n][hc] f16 = Wh_dir[g][k][hc], n = (k<<2)|g
__global__ __launch_bounds__(256) void prep_wh16(
    const float* __restrict__ WhF, const float* __restrict__ WhB, _Float16* __restrict__ whr) {
  int e = blockIdx.x * 256 + threadIdx.x;
  int hc = e & 511;
  int n = (e >> 9) & 2047;
  int dir = e >> 20;
  int k = n >> 2, g = n & 3;
  const float* Wh = dir ? WhB : WhF;
  whr[e] = (_Float16)Wh[(g * Hd + k) * Hd + hc];
}

// wfc16[dir][v][hc] f16 = Wfc[v][dir*512+hc]
__global__ __launch_bounds__(256) void prep_wfc16(
    const float* __restrict__ Wfc, _Float16* __restrict__ wfc16) {
  int e = blockIdx.x * 256 + threadIdx.x;
  int hc = e & 511;
  int v = (e >> 9) & 127;
  int dir = e >> 16;
  wfc16[e] = (_Float16)Wfc[v * 1024 + dir * 512 + hc];
}

__global__ __launch_bounds__(256) void init_zero(float* __restrict__ p, int n4) {
  int e = blockIdx.x * 256 + threadIdx.x;
  if (e < n4) {
    float4 z; z.x = 0.f; z.y = 0.f; z.z = 0.f; z.w = 0.f;
    ((float4*)p)[e] = z;
  }
}

__global__ __launch_bounds__(256) void init_out(const float* __restrict__ bfc,
                                                float* __restrict__ out) {
  int e = blockIdx.x * 256 + threadIdx.x;
  int v0 = (e & 31) * 4;
  ((float4*)out)[e] = *(const float4*)&bfc[v0];
}

// ---------------- persistent BiLSTM kernel ----------------
// grid = 136 blocks x 256 thr, 1 block/CU (143 KB LDS).
//   bid < 128 : LSTM. dir=bid>>6, mt=(bid&63)>>4 (128 b), nt=bid&15 (128 n = 32 k x 4 gates)
//   bid >= 128: FC.   f=bid-128: dir=f>>2, mt=f&3. Consumes h one phase behind, atomicAdd to out.
// h ring: 3 slots, slot p%3 holds h^p. cnt[grp]: 16 producer increments per iter (release).
// fc_cnt[grp]: FC back-pressure so LSTM can't overwrite a slot FC still reads.
#define BTP 520   // padded LDS row stride (halves): conflict-free-equivalent b128 reads
__global__ __launch_bounds__(256, 1) void bilstm_persist(
    const float* __restrict__ wxt, const int* __restrict__ x,
    const _Float16* __restrict__ whr, const _Float16* __restrict__ wfc16,
    _Float16* __restrict__ hring, int* __restrict__ cnt, float* __restrict__ out) {
  __shared__ _Float16 Bt[128 * BTP];   // 133,120 B: weight tile, resident all 256 iters
  __shared__ _Float16 hT[128 * 40];    // 10,240 B: h transpose staging

  const int tid = threadIdx.x;
  const int lane = tid & 63;
  const int w = tid >> 6;
  const int bid = blockIdx.x;
  const bool isFC = (bid >= 128);
  int dir, mt, nt = 0;
  const _Float16* Bsrc;
  if (isFC) {
    int f = bid - 128; dir = f >> 2; mt = f & 3;
    Bsrc = wfc16 + dir * (128 * 512);
  } else {
    dir = bid >> 6; mt = (bid & 63) >> 4; nt = bid & 15;
    Bsrc = whr + ((size_t)(dir * 2048 + nt * 128)) * 512;
  }
  const int b0 = mt * 128;
  const int wn0 = (w & 1) * 64;        // n (or v) wave offset
  const int wb0 = (w >> 1) * 64;       // b wave offset
  const int grp = dir * 4 + mt;
  int* cw = cnt + grp * 16;
  int* fcw = cnt + 128 + grp * 16;

  // stage weight tile into padded LDS (once)
  for (int e = tid; e < 128 * 64; e += 256) {
    int row = e >> 6, seg = e & 63;
    *(half8*)&Bt[row * BTP + seg * 8] = *(const half8*)&Bsrc[row * 512 + seg * 8];
  }
  __syncthreads();

  // per-thread constant offsets
  int aoff[4], boff[4];
#pragma unroll
  for (int i = 0; i < 4; ++i) {
    aoff[i] = (b0 + wb0 + i * 16 + (lane & 15)) * 512 + (lane >> 4) * 8;  // h frag
    boff[i] = (wn0 + i * 16 + (lane & 15)) * BTP + (lane >> 4) * 8;      // W frag
  }
  const int klq = (wn0 >> 2) + (lane >> 4);  // + ni*4 -> k-local in [0,32)

  float creg[4][4];
#pragma unroll
  for (int mi = 0; mi < 4; ++mi)
#pragma unroll
    for (int ni = 0; ni < 4; ++ni) creg[mi][ni] = 0.f;

  for (int it = 0; it < 256; ++it) {
    const int tcur = dir ? (255 - it) : it;
    const _Float16* hsrc = hring + (size_t)((isFC ? (it + 1) : it) % 3) * 524288 + dir * 262144;
    _Float16* hdst = hring + (size_t)((it + 1) % 3) * 524288 + dir * 262144;

    // ---- pre-spin prefetch of static data (x, wxt) ----
    float4 wpre[4][4];
    if (!isFC) {
      int xv[4];
#pragma unroll
      for (int mi = 0; mi < 4; ++mi)
        xv[mi] = x[(b0 + wb0 + mi * 16 + (lane & 15)) * Sd + tcur];
#pragma unroll
      for (int mi = 0; mi < 4; ++mi)
#pragma unroll
        for (int ni = 0; ni < 4; ++ni)
          wpre[mi][ni] = *(const float4*)&wxt[(size_t)(dir * Vd + xv[mi]) * 2048 +
                                              (nt * 32 + klq + ni * 4) * 4];
    }

    // ---- group barrier: wait for h^it (LSTM) / h^{it+1} (FC) ----
    if (tid == 0) {
      if (isFC) {
        int tgt = 16 * (it + 1);
        while (__hip_atomic_load(cw, __ATOMIC_ACQUIRE, __HIP_MEMORY_SCOPE_AGENT) < tgt)
          __builtin_amdgcn_s_sleep(2);
      } else {
        if (it > 0) {
          int tgt = 16 * it;
          while (__hip_atomic_load(cw, __ATOMIC_ACQUIRE, __HIP_MEMORY_SCOPE_AGENT) < tgt)
            __builtin_amdgcn_s_sleep(2);
        }
        if (it >= 3) {  // ring safety: FC must be done reading the slot we overwrite
          int tgt = it - 2;
          while (__hip_atomic_load(fcw, __ATOMIC_ACQUIRE, __HIP_MEMORY_SCOPE_AGENT) < tgt)
            __builtin_amdgcn_s_sleep(2);
        }
      }
    }
    __syncthreads();

    // ---- K loop: 16 chunks of 32, no barriers. B from LDS, h global->reg dbuf ----
    float4v acc[4][4];
#pragma unroll
    for (int mi = 0; mi < 4; ++mi)
#pragma unroll
      for (int ni = 0; ni < 4; ++ni) acc[mi][ni] = (float4v)0.f;

    half8 bf0[4], bf1[4];
#pragma unroll
    for (int mi = 0; mi < 4; ++mi) bf0[mi] = *(const half8*)(hsrc + aoff[mi]);
#pragma unroll
    for (int kc = 0; kc < 16; ++kc) {
      half8 af[4];
#pragma unroll
      for (int ni = 0; ni < 4; ++ni) af[ni] = *(const half8*)&Bt[boff[ni] + kc * 32];
      if (kc < 15) {
#pragma unroll
        for (int mi = 0; mi < 4; ++mi)
          ((kc & 1) ? bf0 : bf1)[mi] = *(const half8*)(hsrc + aoff[mi] + (kc + 1) * 32);
      }
#pragma unroll
      for (int mi = 0; mi < 4; ++mi) {
        half8 bcur = ((kc & 1) ? bf1 : bf0)[mi];
#pragma unroll
        for (int ni = 0; ni < 4; ++ni)
          acc[mi][ni] = __builtin_amdgcn_mfma_f32_16x16x32_f16(af[ni], bcur, acc[mi][ni], 0, 0, 0);
      }
    }

    if (isFC) {
      // ---- FC epilogue: atomicAdd into bias-initialized out ----
#pragma unroll
      for (int mi = 0; mi < 4; ++mi) {
        int b = b0 + wb0 + mi * 16 + (lane & 15);
        size_t rbase = ((size_t)b * Sd + tcur) * Vd;
#pragma unroll
        for (int ni = 0; ni < 4; ++ni) {
          int v = wn0 + ni * 16 + (lane >> 4) * 4;
#pragma unroll
          for (int r2 = 0; r2 < 4; ++r2)
            atomicAdd(&out[rbase + v + r2], acc[mi][ni][r2]);
        }
      }
      __syncthreads();
      if (tid == 0)
        __hip_atomic_fetch_add(fcw, 1, __ATOMIC_RELEASE, __HIP_MEMORY_SCOPE_AGENT);
    } else {
      // ---- LSTM epilogue: gates in-register, c in VGPRs, h via LDS transpose ----
#pragma unroll
      for (int mi = 0; mi < 4; ++mi) {
        int bl = wb0 + mi * 16 + (lane & 15);
#pragma unroll
        for (int ni = 0; ni < 4; ++ni) {
          int kl = klq + ni * 4;
          float gi = sigf(acc[mi][ni][0] + wpre[mi][ni].x);
          float gf = sigf(acc[mi][ni][1] + wpre[mi][ni].y);
          float go = sigf(acc[mi][ni][2] + wpre[mi][ni].z);
          float gg = tanhfast(acc[mi][ni][3] + wpre[mi][ni].w);
          float cn = gf * creg[mi][ni] + gi * gg;
          creg[mi][ni] = cn;
          hT[bl * 40 + kl] = (_Float16)(go * tanhfast(cn));
        }
      }
      __syncthreads();
      // coalesced h store: lane pattern gives full 64-B lines
#pragma unroll
      for (int j = 0; j < 2; ++j) {
        int bl = (tid >> 2) + j * 64;
        int seg = tid & 3;
        half8 hv = *(const half8*)&hT[bl * 40 + seg * 8];
        *(half8*)(hdst + (b0 + bl) * 512 + nt * 32 + seg * 8) = hv;
      }
      __syncthreads();  // drains vmcnt: h stores complete before release
      if (tid == 0)
        __hip_atomic_fetch_add(cw, 1, __ATOMIC_RELEASE, __HIP_MEMORY_SCOPE_AGENT);
    }
  }
}

extern "C" void kernel_launch(void* const* d_in, const int* in_sizes, int n_in,
                              void* d_out, int out_size, void* d_ws, size_t ws_size,
                              hipStream_t stream) {
  const int* x      = (const int*)d_in[0];
  const float* WxF  = (const float*)d_in[1];
  const float* WhF  = (const float*)d_in[2];
  const float* bxF  = (const float*)d_in[3];
  const float* bhF  = (const float*)d_in[4];
  const float* WxB  = (const float*)d_in[5];
  const float* WhB  = (const float*)d_in[6];
  const float* bxB  = (const float*)d_in[7];
  const float* bhB  = (const float*)d_in[8];
  const float* Wfc  = (const float*)d_in[9];
  const float* bfc  = (const float*)d_in[10];
  float* out = (float*)d_out;

  // ws layout (float offsets):
  //   wxt    @ 0          len 524,288   (2 MB)
  //   wh16   @ 524,288    len 1,048,576 (2,097,152 halves)
  //   wfc16  @ 1,572,864  len 65,536    (131,072 halves)
  //   cnt    @ 1,638,400  len 256       (ints)
  //   hring  @ 1,638,656  len 786,432   (3 slots x 524,288 halves)
  // total ~9.7 MB
  float* ws = (float*)d_ws;
  float* wxt = ws;
  _Float16* wh16 = (_Float16*)(ws + 524288);
  _Float16* wfc16 = (_Float16*)(ws + 1572864);
  int* cnt = (int*)(ws + 1638400);
  _Float16* hring = (_Float16*)(ws + 1638656);

  prep_wxt<<<2048, 256, 0, stream>>>(WxF, bxF, bhF, WxB, bxB, bhB, wxt);
  prep_wh16<<<8192, 256, 0, stream>>>(WhF, WhB, wh16);
  prep_wfc16<<<512, 256, 0, stream>>>(Wfc, wfc16);
  // zero cnt(256 fl) + h ring slot 0 (262,144 fl) contiguously: 65,600 float4
  init_zero<<<257, 256, 0, stream>>>(ws + 1638400, 65600);
  init_out<<<16384, 256, 0, stream>>>(bfc, out);

  bilstm_persist<<<136, 256, 0, stream>>>(wxt, x, wh16, wfc16, hring, cnt, out);
}